// Round 4
// baseline (935.882 us; speedup 1.0000x reference)
//
#include <hip/hip_runtime.h>
#include <hip/hip_bf16.h>
#include <math.h>

#define DD 512
#define EPSF 1e-8f
#define BM 128
#define BN 128
#define BK 32
#define FBIG 3.402823466e+38f
#define NPAD 200064

typedef __bf16 bf16_t;
typedef __bf16 bf16x4 __attribute__((ext_vector_type(4)));
typedef __bf16 bf16x8 __attribute__((ext_vector_type(8)));
typedef float f32x4 __attribute__((ext_vector_type(4)));

// ---------------- W fp32 -> bf16 (native [j][k] layout) ----------------
__global__ void k_convW(const float* __restrict__ W, bf16_t* __restrict__ Wb) {
    int i = blockIdx.x * blockDim.x + threadIdx.x;
    float4 v = ((const float4*)W)[i];
    bf16x4 o;
    o[0] = (bf16_t)v.x; o[1] = (bf16_t)v.y; o[2] = (bf16_t)v.z; o[3] = (bf16_t)v.w;
    ((bf16x4*)Wb)[i] = o;
}

// ---------------- partial column sums, contiguous row range per block ----------------
__global__ void k_colsum(const float* __restrict__ z, float* __restrict__ part, int N, int rpb) {
    int t = threadIdx.x;                 // 256
    int b = blockIdx.x;                  // 1024
    int col4 = t & 127, sub = t >> 7;
    int r0 = b * rpb, r1 = min(r0 + rpb, N);
    const float4* z4 = (const float4*)z;
    float4 acc = make_float4(0.f, 0.f, 0.f, 0.f);
    #pragma unroll 4
    for (int r = r0 + sub; r < r1; r += 2) {
        float4 v = z4[(size_t)r * 128 + col4];
        acc.x += v.x; acc.y += v.y; acc.z += v.z; acc.w += v.w;
    }
    __shared__ float4 sm[128];
    if (sub == 1) sm[col4] = acc;
    __syncthreads();
    if (sub == 0) {
        float4 o = sm[col4];
        acc.x += o.x; acc.y += o.y; acc.z += o.z; acc.w += o.w;
        ((float4*)(part + (size_t)b * DD))[col4] = acc;
    }
}

// ---------------- weighted partial column sums ----------------
__global__ void k_wcolsum(const float* __restrict__ z, const float* __restrict__ d2,
                          const float* __restrict__ d2min, const float* __restrict__ sinvp,
                          float* __restrict__ part, int N, int rpb) {
    int t = threadIdx.x;
    int b = blockIdx.x;
    int col4 = t & 127, sub = t >> 7;
    int r0 = b * rpb, r1 = min(r0 + rpb, N);
    float m  = d2min[0];
    float is = sinvp[0];
    const float4* z4 = (const float4*)z;
    float4 acc = make_float4(0.f, 0.f, 0.f, 0.f);
    #pragma unroll 4
    for (int r = r0 + sub; r < r1; r += 2) {
        float w = __expf(-2.0f * (d2[r] - m)) * is;
        float4 v = z4[(size_t)r * 128 + col4];
        acc.x += w * v.x; acc.y += w * v.y; acc.z += w * v.z; acc.w += w * v.w;
    }
    __shared__ float4 sm[128];
    if (sub == 1) sm[col4] = acc;
    __syncthreads();
    if (sub == 0) {
        float4 o = sm[col4];
        acc.x += o.x; acc.y += o.y; acc.z += o.z; acc.w += o.w;
        ((float4*)(part + (size_t)b * DD))[col4] = acc;
    }
}

// reduce 1024 partial vectors -> one [512] vector; one block per column
__global__ void k_reduce1024(const float* __restrict__ part, float* __restrict__ outv, float scale) {
    __shared__ float sm[256];
    int j = blockIdx.x;
    int t = threadIdx.x;
    float s = part[(size_t)t * DD + j] + part[(size_t)(t + 256) * DD + j]
            + part[(size_t)(t + 512) * DD + j] + part[(size_t)(t + 768) * DD + j];
    sm[t] = s;
    __syncthreads();
    for (int st = 128; st > 0; st >>= 1) {
        if (t < st) sm[t] += sm[t + st];
        __syncthreads();
    }
    if (t == 0) outv[j] = sm[0] * scale;
}

// ---------------- d2 + online softmax partials; quarter-wave per row ----------------
__global__ void k_d2s(const float* __restrict__ z, const float* __restrict__ cbar,
                      float* __restrict__ d2, float* __restrict__ mpart,
                      float* __restrict__ spart, int N) {
    int t = threadIdx.x;                 // 256
    int lane = t & 63, wv = t >> 6;
    int l15 = lane & 15, r4 = lane >> 4;
    const float4* c4 = (const float4*)cbar;
    float4 cf[8];
    #pragma unroll
    for (int q = 0; q < 8; ++q) cf[q] = c4[q * 16 + l15];
    int gw = (blockIdx.x * 256 + t) >> 6;
    int nw = (gridDim.x * 256) >> 6;
    float m = FBIG, s = 0.f;
    #pragma unroll 2
    for (int r = gw * 4 + r4; r < N; r += nw * 4) {
        const float4* zr = (const float4*)(z + (size_t)r * DD);
        float sum = 0.f;
        #pragma unroll
        for (int q = 0; q < 8; ++q) {
            float4 v = zr[q * 16 + l15];
            float d;
            d = v.x - cf[q].x; sum += d * d;
            d = v.y - cf[q].y; sum += d * d;
            d = v.z - cf[q].z; sum += d * d;
            d = v.w - cf[q].w; sum += d * d;
        }
        #pragma unroll
        for (int off = 1; off < 16; off <<= 1) sum += __shfl_xor(sum, off, 64);
        if (l15 == 0) d2[r] = sum;
        float nm = fminf(m, sum);
        s = s * __expf(-2.0f * (m - nm)) + __expf(-2.0f * (sum - nm));
        m = nm;
    }
    // merge across the 4 row-groups (all lanes in a group hold identical state)
    #pragma unroll
    for (int off = 16; off < 64; off <<= 1) {
        float m2 = __shfl_xor(m, off, 64);
        float s2 = __shfl_xor(s, off, 64);
        float nm = fminf(m, m2);
        s = s * __expf(-2.0f * (m - nm)) + s2 * __expf(-2.0f * (m2 - nm));
        m = nm;
    }
    __shared__ float smm[4], sms[4];
    if (lane == 0) { smm[wv] = m; sms[wv] = s; }
    __syncthreads();
    if (t == 0) {
        float M = fminf(fminf(smm[0], smm[1]), fminf(smm[2], smm[3]));
        float S = 0.f;
        #pragma unroll
        for (int i = 0; i < 4; ++i) S += sms[i] * __expf(-2.0f * (smm[i] - M));
        mpart[blockIdx.x] = M;
        spart[blockIdx.x] = S;
    }
}

// combine 1024 (m,s) partials -> d2min, 1/sumexp
__global__ void k_combine(const float* __restrict__ mpart, const float* __restrict__ spart,
                          float* __restrict__ d2min, float* __restrict__ sinvp) {
    __shared__ float smm[256], sms[256];
    int t = threadIdx.x;
    float M = FBIG, S = 0.f;
    for (int i = t; i < 1024; i += 256) {
        float m2 = mpart[i], s2 = spart[i];
        float nm = fminf(M, m2);
        S = S * __expf(-2.0f * (M - nm)) + s2 * __expf(-2.0f * (m2 - nm));
        M = nm;
    }
    smm[t] = M; sms[t] = S;
    __syncthreads();
    for (int st = 128; st > 0; st >>= 1) {
        if (t < st) {
            float m2 = smm[t + st], s2 = sms[t + st];
            float nm = fminf(smm[t], m2);
            sms[t] = sms[t] * __expf(-2.0f * (smm[t] - nm)) + s2 * __expf(-2.0f * (m2 - nm));
            smm[t] = nm;
        }
        __syncthreads();
    }
    if (t == 0) { d2min[0] = smm[0]; sinvp[0] = 1.0f / sms[0]; }
}

// ---------------- cnorm_inv ----------------
__global__ void k_cnorm(const float* __restrict__ cvec, float* __restrict__ outp) {
    __shared__ float sm[512];
    float v = cvec[threadIdx.x];
    sm[threadIdx.x] = v * v;
    __syncthreads();
    for (int st = 256; st > 0; st >>= 1) {
        if (threadIdx.x < st) sm[threadIdx.x] += sm[threadIdx.x + st];
        __syncthreads();
    }
    if (threadIdx.x == 0) outp[0] = 1.0f / fmaxf(sqrtf(sm[0]), EPSF);
}

// ---------------- MFMA GEMM, m97-shape: 256 thr, 128x128 tile, 3 blocks/CU ----------------
// grid (4, 1563): x = col-block, y = row-group. Writes per-(row,colblock)
// sq/dot partials; k_final combines.
__global__ __launch_bounds__(256, 3) void k_gemm(
    const float* __restrict__ z, const bf16_t* __restrict__ Wb,
    const float* __restrict__ bvec, const float* __restrict__ cvec,
    float* __restrict__ sqp, float* __restrict__ dtp, int N)
{
    __shared__ bf16_t As[BM * BK];      // 8 KB [m][k]
    __shared__ bf16_t Bs[BN * BK];      // 8 KB [n][k]
    __shared__ float psq[BM][2];
    __shared__ float pdt[BM][2];

    const int t    = threadIdx.x;
    const int lane = t & 63;
    const int wv   = t >> 6;            // 0..3
    const int wr   = wv >> 1;           // 0..1
    const int wc   = wv & 1;            // 0..1
    const int quad = lane >> 4;
    const int l15  = lane & 15;
    const int cb   = blockIdx.x;        // col-block 0..3
    const int row0 = blockIdx.y * BM;

    // A: thread t -> row t>>1, k-half (t&1)*16 floats; clamp OOB rows (safe garbage)
    const int arow = t >> 1;
    const int ah   = t & 1;
    int rowe = row0 + arow; if (rowe >= N) rowe = N - 1;
    const float4* zp4 = (const float4*)(z + (size_t)rowe * DD + ah * 16);

    // B DMA: round q: j = q*64 + (t>>2), 16B at k-off (t&3)*8  (LDS dest = lane*16 contiguous)
    const bf16_t* bp = Wb + (size_t)(cb * BN + (t >> 2)) * DD + (t & 3) * 8;

    f32x4 acc[4][4];
    #pragma unroll
    for (int a = 0; a < 4; ++a)
        #pragma unroll
        for (int b = 0; b < 4; ++b) acc[a][b] = (f32x4){0.f, 0.f, 0.f, 0.f};

    float4 v0 = zp4[0], v1 = zp4[1], v2 = zp4[2], v3 = zp4[3];   // prefetch chunk 0

    for (int kc = 0; kc < DD; kc += BK) {
        if (kc) __syncthreads();        // #1: previous compute done, LDS reusable

        // B: 2 DMA rounds of 256 lanes x 16 B
        #pragma unroll
        for (int q = 0; q < 2; ++q) {
            int ldsoff = __builtin_amdgcn_readfirstlane(q * 4096 + wv * 1024);
            __builtin_amdgcn_global_load_lds(
                (const __attribute__((address_space(1))) unsigned int*)(const void*)(bp + (size_t)q * 64 * DD + kc),
                (__attribute__((address_space(3))) unsigned int*)(void*)((char*)Bs + ldsoff),
                16, 0, 0);
        }
        // A: convert prefetched regs -> LDS (2 x b128)
        bf16x8 lo, hi;
        lo[0]=(bf16_t)v0.x; lo[1]=(bf16_t)v0.y; lo[2]=(bf16_t)v0.z; lo[3]=(bf16_t)v0.w;
        lo[4]=(bf16_t)v1.x; lo[5]=(bf16_t)v1.y; lo[6]=(bf16_t)v1.z; lo[7]=(bf16_t)v1.w;
        hi[0]=(bf16_t)v2.x; hi[1]=(bf16_t)v2.y; hi[2]=(bf16_t)v2.z; hi[3]=(bf16_t)v2.w;
        hi[4]=(bf16_t)v3.x; hi[5]=(bf16_t)v3.y; hi[6]=(bf16_t)v3.z; hi[7]=(bf16_t)v3.w;
        *(bf16x8*)(As + arow * BK + ah * 16)     = lo;
        *(bf16x8*)(As + arow * BK + ah * 16 + 8) = hi;

        __syncthreads();                // #2: drains vmcnt (DMA) + lgkm (writes)

        if (kc + BK < DD) {             // prefetch next A chunk during compute
            int kf = (kc + BK) >> 2;
            v0 = zp4[kf]; v1 = zp4[kf + 1]; v2 = zp4[kf + 2]; v3 = zp4[kf + 3];
        }

        bf16x8 af[4];
        #pragma unroll
        for (int rt = 0; rt < 4; ++rt)
            af[rt] = *(const bf16x8*)(As + (wr * 64 + rt * 16 + l15) * BK + quad * 8);
        #pragma unroll
        for (int ct = 0; ct < 4; ++ct) {
            bf16x8 bfv = *(const bf16x8*)(Bs + (wc * 64 + ct * 16 + l15) * BK + quad * 8);
            #pragma unroll
            for (int rt = 0; rt < 4; ++rt)
                acc[rt][ct] = __builtin_amdgcn_mfma_f32_16x16x32_bf16(af[rt], bfv, acc[rt][ct], 0, 0, 0);
        }
    }

    // epilogue: x = acc + b[col]; per-row partial sq and dot(c) over this col-block
    float bc[4], cc[4];
    #pragma unroll
    for (int ct = 0; ct < 4; ++ct) {
        int col = cb * BN + wc * 64 + ct * 16 + l15;
        bc[ct] = bvec[col];
        cc[ct] = cvec[col];
    }
    #pragma unroll
    for (int rt = 0; rt < 4; ++rt) {
        #pragma unroll
        for (int rg = 0; rg < 4; ++rg) {
            float sq = 0.f, dt = 0.f;
            #pragma unroll
            for (int ct = 0; ct < 4; ++ct) {
                float x = acc[rt][ct][rg] + bc[ct];
                sq += x * x;
                dt += x * cc[ct];
            }
            #pragma unroll
            for (int off = 1; off < 16; off <<= 1) {
                sq += __shfl_xor(sq, off, 64);
                dt += __shfl_xor(dt, off, 64);
            }
            if (l15 == 0) {
                int rl = wr * 64 + rt * 16 + quad * 4 + rg;
                psq[rl][wc] = sq;
                pdt[rl][wc] = dt;
            }
        }
    }
    __syncthreads();
    if (t < BM) {
        int r = row0 + t;
        if (r < N) {
            sqp[(size_t)cb * NPAD + r] = psq[t][0] + psq[t][1];
            dtp[(size_t)cb * NPAD + r] = pdt[t][0] + pdt[t][1];
        }
    }
}

// ---------------- combine 4 col-block partials -> dist ----------------
__global__ void k_final(const float* __restrict__ sqp, const float* __restrict__ dtp,
                        const float* __restrict__ cninv, float* __restrict__ out, int N) {
    int r = blockIdx.x * blockDim.x + threadIdx.x;
    if (r < N) {
        float sq = sqp[r] + sqp[NPAD + r] + sqp[2 * NPAD + r] + sqp[3 * NPAD + r];
        float dt = dtp[r] + dtp[NPAD + r] + dtp[2 * NPAD + r] + dtp[3 * NPAD + r];
        out[r] = 1.0f - dt * cninv[0] / fmaxf(sqrtf(sq), EPSF);
    }
}

extern "C" void kernel_launch(void* const* d_in, const int* in_sizes, int n_in,
                              void* d_out, int out_size, void* d_ws, size_t ws_size,
                              hipStream_t stream)
{
    const float* z = (const float*)d_in[0];
    const float* W = (const float*)d_in[1];
    const float* b = (const float*)d_in[2];
    float* out = (float*)d_out;
    int N = in_sizes[0] / DD;

    float* ws = (float*)d_ws;
    size_t off = 0;
    float* part  = ws + off; off += (size_t)1024 * DD;
    float* cbar  = ws + off; off += DD;
    float* d2    = ws + off; off += (size_t)NPAD;
    float* mpart = ws + off; off += 1024;
    float* spart = ws + off; off += 1024;
    float* d2min = ws + off; off += 1;
    float* sinvp = ws + off; off += 1;
    float* cvec  = ws + off; off += DD;
    float* cninv = ws + off; off += 1;
    off = (off + 3) & ~(size_t)3;
    float* sqp   = ws + off; off += (size_t)4 * NPAD;
    float* dtp   = ws + off; off += (size_t)4 * NPAD;
    bf16_t* Wb   = (bf16_t*)(ws + off);

    int rpb = (N + 1023) / 1024;

    k_convW<<<256, 256, 0, stream>>>(W, Wb);
    k_colsum<<<1024, 256, 0, stream>>>(z, part, N, rpb);
    k_reduce1024<<<DD, 256, 0, stream>>>(part, cbar, 1.0f / (float)N);
    k_d2s<<<1024, 256, 0, stream>>>(z, cbar, d2, mpart, spart, N);
    k_combine<<<1, 256, 0, stream>>>(mpart, spart, d2min, sinvp);
    k_wcolsum<<<1024, 256, 0, stream>>>(z, d2, d2min, sinvp, part, N, rpb);
    k_reduce1024<<<DD, 256, 0, stream>>>(part, cvec, 1.0f);
    k_cnorm<<<1, DD, 0, stream>>>(cvec, cninv);
    dim3 grid(4, (N + BM - 1) / BM);
    k_gemm<<<grid, 256, 0, stream>>>(z, Wb, b, cvec, sqp, dtp, N);
    k_final<<<(N + 255) / 256, 256, 0, stream>>>(sqp, dtp, cninv, out, N);
}

// Round 5
// 903.340 us; speedup vs baseline: 1.0360x; 1.0360x over previous
//
#include <hip/hip_runtime.h>
#include <hip/hip_bf16.h>
#include <math.h>

#define DD 512
#define EPSF 1e-8f
#define BM 128
#define BN 128
#define BK 32
#define FBIG 3.402823466e+38f
#define NPART 2048

typedef __bf16 bf16_t;
typedef __bf16 bf16x4_t __attribute__((ext_vector_type(4)));
typedef __bf16 bf16x8_t __attribute__((ext_vector_type(8)));
typedef float f32x4 __attribute__((ext_vector_type(4)));

__device__ inline float bf2f(unsigned short u) {
    return __uint_as_float(((unsigned int)u) << 16);
}

// ---------------- W fp32 -> bf16 (native [j][k] layout) ----------------
__global__ void k_convW(const float* __restrict__ W, bf16_t* __restrict__ Wb) {
    int i = blockIdx.x * blockDim.x + threadIdx.x;
    float4 v = ((const float4*)W)[i];
    bf16x4_t o;
    o[0] = (bf16_t)v.x; o[1] = (bf16_t)v.y; o[2] = (bf16_t)v.z; o[3] = (bf16_t)v.w;
    ((bf16x4_t*)Wb)[i] = o;
}

// ---------------- partial column sums + optional z->bf16 conversion ----------------
template<bool CONV>
__global__ void k_colsum(const float* __restrict__ z, bf16_t* __restrict__ zb,
                         float* __restrict__ part, int N, int rpb) {
    int t = threadIdx.x;                 // 256
    int b = blockIdx.x;                  // NPART
    int col4 = t & 127, sub = t >> 7;
    int r0 = b * rpb, r1 = min(r0 + rpb, N);
    const float4* z4 = (const float4*)z;
    float4 acc = make_float4(0.f, 0.f, 0.f, 0.f);
    #pragma unroll 4
    for (int r = r0 + sub; r < r1; r += 2) {
        float4 v = z4[(size_t)r * 128 + col4];
        if (CONV) {
            bf16x4_t o;
            o[0] = (bf16_t)v.x; o[1] = (bf16_t)v.y; o[2] = (bf16_t)v.z; o[3] = (bf16_t)v.w;
            ((bf16x4_t*)zb)[(size_t)r * 128 + col4] = o;
        }
        acc.x += v.x; acc.y += v.y; acc.z += v.z; acc.w += v.w;
    }
    __shared__ float4 sm[128];
    if (sub == 1) sm[col4] = acc;
    __syncthreads();
    if (sub == 0) {
        float4 o = sm[col4];
        acc.x += o.x; acc.y += o.y; acc.z += o.z; acc.w += o.w;
        ((float4*)(part + (size_t)b * DD))[col4] = acc;
    }
}

// ---------------- weighted partial column sums (fp32 z fallback) ----------------
__global__ void k_wcolsum_f(const float* __restrict__ z, const float* __restrict__ d2,
                            const float* __restrict__ d2min, const float* __restrict__ sinvp,
                            float* __restrict__ part, int N, int rpb) {
    int t = threadIdx.x;
    int b = blockIdx.x;
    int col4 = t & 127, sub = t >> 7;
    int r0 = b * rpb, r1 = min(r0 + rpb, N);
    float m  = d2min[0];
    float is = sinvp[0];
    const float4* z4 = (const float4*)z;
    float4 acc = make_float4(0.f, 0.f, 0.f, 0.f);
    #pragma unroll 4
    for (int r = r0 + sub; r < r1; r += 2) {
        float w = __expf(-2.0f * (d2[r] - m)) * is;
        float4 v = z4[(size_t)r * 128 + col4];
        acc.x += w * v.x; acc.y += w * v.y; acc.z += w * v.z; acc.w += w * v.w;
    }
    __shared__ float4 sm[128];
    if (sub == 1) sm[col4] = acc;
    __syncthreads();
    if (sub == 0) {
        float4 o = sm[col4];
        acc.x += o.x; acc.y += o.y; acc.z += o.z; acc.w += o.w;
        ((float4*)(part + (size_t)b * DD))[col4] = acc;
    }
}

// ---------------- weighted partial column sums (bf16 zb) ----------------
__global__ void k_wcolsum_b(const bf16_t* __restrict__ zb, const float* __restrict__ d2,
                            const float* __restrict__ d2min, const float* __restrict__ sinvp,
                            float* __restrict__ part, int N, int rpb) {
    int t = threadIdx.x;
    int b = blockIdx.x;
    int col4 = t & 127, sub = t >> 7;
    int r0 = b * rpb, r1 = min(r0 + rpb, N);
    float m  = d2min[0];
    float is = sinvp[0];
    const ushort4* z4 = (const ushort4*)zb;
    float4 acc = make_float4(0.f, 0.f, 0.f, 0.f);
    #pragma unroll 8
    for (int r = r0 + sub; r < r1; r += 2) {
        float w = __expf(-2.0f * (d2[r] - m)) * is;
        ushort4 u = z4[(size_t)r * 128 + col4];
        acc.x += w * bf2f(u.x); acc.y += w * bf2f(u.y);
        acc.z += w * bf2f(u.z); acc.w += w * bf2f(u.w);
    }
    __shared__ float4 sm[128];
    if (sub == 1) sm[col4] = acc;
    __syncthreads();
    if (sub == 0) {
        float4 o = sm[col4];
        acc.x += o.x; acc.y += o.y; acc.z += o.z; acc.w += o.w;
        ((float4*)(part + (size_t)b * DD))[col4] = acc;
    }
}

// reduce NPART partial vectors -> one [512] vector; one block per column
__global__ void k_reduceP(const float* __restrict__ part, float* __restrict__ outv, float scale) {
    __shared__ float sm[256];
    int j = blockIdx.x;
    int t = threadIdx.x;
    float s = 0.f;
    #pragma unroll
    for (int p = 0; p < NPART / 256; ++p) s += part[(size_t)(p * 256 + t) * DD + j];
    sm[t] = s;
    __syncthreads();
    for (int st = 128; st > 0; st >>= 1) {
        if (t < st) sm[t] += sm[t + st];
        __syncthreads();
    }
    if (t == 0) outv[j] = sm[0] * scale;
}

// ---------------- d2 + online softmax partials; quarter-wave per row ----------------
__global__ void k_d2s(const float* __restrict__ z, const float* __restrict__ cbar,
                      float* __restrict__ d2, float* __restrict__ mpart,
                      float* __restrict__ spart, int N) {
    int t = threadIdx.x;                 // 256
    int lane = t & 63, wv = t >> 6;
    int l15 = lane & 15, r4 = lane >> 4;
    const float4* c4 = (const float4*)cbar;
    float4 cf[8];
    #pragma unroll
    for (int q = 0; q < 8; ++q) cf[q] = c4[q * 16 + l15];
    int gw = (blockIdx.x * 256 + t) >> 6;
    int nw = (gridDim.x * 256) >> 6;
    float m = FBIG, s = 0.f;
    #pragma unroll 2
    for (int r = gw * 4 + r4; r < N; r += nw * 4) {
        const float4* zr = (const float4*)(z + (size_t)r * DD);
        float sum = 0.f;
        #pragma unroll
        for (int q = 0; q < 8; ++q) {
            float4 v = zr[q * 16 + l15];
            float d;
            d = v.x - cf[q].x; sum += d * d;
            d = v.y - cf[q].y; sum += d * d;
            d = v.z - cf[q].z; sum += d * d;
            d = v.w - cf[q].w; sum += d * d;
        }
        #pragma unroll
        for (int off = 1; off < 16; off <<= 1) sum += __shfl_xor(sum, off, 64);
        if (l15 == 0) d2[r] = sum;
        float nm = fminf(m, sum);
        s = s * __expf(-2.0f * (m - nm)) + __expf(-2.0f * (sum - nm));
        m = nm;
    }
    #pragma unroll
    for (int off = 16; off < 64; off <<= 1) {
        float m2 = __shfl_xor(m, off, 64);
        float s2 = __shfl_xor(s, off, 64);
        float nm = fminf(m, m2);
        s = s * __expf(-2.0f * (m - nm)) + s2 * __expf(-2.0f * (m2 - nm));
        m = nm;
    }
    __shared__ float smm[4], sms[4];
    if (lane == 0) { smm[wv] = m; sms[wv] = s; }
    __syncthreads();
    if (t == 0) {
        float M = fminf(fminf(smm[0], smm[1]), fminf(smm[2], smm[3]));
        float S = 0.f;
        #pragma unroll
        for (int i = 0; i < 4; ++i) S += sms[i] * __expf(-2.0f * (smm[i] - M));
        mpart[blockIdx.x] = M;
        spart[blockIdx.x] = S;
    }
}

// combine NPART (m,s) partials -> d2min, 1/sumexp
__global__ void k_combine(const float* __restrict__ mpart, const float* __restrict__ spart,
                          float* __restrict__ d2min, float* __restrict__ sinvp) {
    __shared__ float smm[256], sms[256];
    int t = threadIdx.x;
    float M = FBIG, S = 0.f;
    for (int i = t; i < NPART; i += 256) {
        float m2 = mpart[i], s2 = spart[i];
        float nm = fminf(M, m2);
        S = S * __expf(-2.0f * (M - nm)) + s2 * __expf(-2.0f * (m2 - nm));
        M = nm;
    }
    smm[t] = M; sms[t] = S;
    __syncthreads();
    for (int st = 128; st > 0; st >>= 1) {
        if (t < st) {
            float m2 = smm[t + st], s2 = sms[t + st];
            float nm = fminf(smm[t], m2);
            sms[t] = sms[t] * __expf(-2.0f * (smm[t] - nm)) + s2 * __expf(-2.0f * (m2 - nm));
            smm[t] = nm;
        }
        __syncthreads();
    }
    if (t == 0) { d2min[0] = smm[0]; sinvp[0] = 1.0f / sms[0]; }
}

// ---------------- cnorm_inv ----------------
__global__ void k_cnorm(const float* __restrict__ cvec, float* __restrict__ outp) {
    __shared__ float sm[512];
    float v = cvec[threadIdx.x];
    sm[threadIdx.x] = v * v;
    __syncthreads();
    for (int st = 256; st > 0; st >>= 1) {
        if (threadIdx.x < st) sm[threadIdx.x] += sm[threadIdx.x + st];
        __syncthreads();
    }
    if (threadIdx.x == 0) outp[0] = 1.0f / fmaxf(sqrtf(sm[0]), EPSF);
}

// ---------------- MFMA GEMM: 256 thr, 128x128 tile, split-4 cols ----------------
// ZB=true: A staged from bf16 zb via global_load_lds (no VALU in K-loop).
// ZB=false: fallback, A prefetched fp32 + converted (round-4 path).
template<bool ZB>
__global__ __launch_bounds__(256, 4) void k_gemm(
    const float* __restrict__ z, const bf16_t* __restrict__ zb,
    const bf16_t* __restrict__ Wb, const float* __restrict__ bvec,
    const float* __restrict__ cvec, float* __restrict__ sqp, float* __restrict__ dtp,
    int N, int npad)
{
    __shared__ bf16_t As[BM * BK];      // 8 KB [m][k]
    __shared__ bf16_t Bs[BN * BK];      // 8 KB [n][k]
    __shared__ float psq[BM][2];
    __shared__ float pdt[BM][2];

    const int t    = threadIdx.x;
    const int lane = t & 63;
    const int wv   = t >> 6;            // 0..3
    const int wr   = wv >> 1;
    const int wc   = wv & 1;
    const int quad = lane >> 4;
    const int l15  = lane & 15;
    const int cb   = blockIdx.x;        // col-block 0..3
    const int row0 = blockIdx.y * BM;

    // B DMA: round q: col = cb*128 + q*64 + (t>>2), 16 B at elem-off (t&3)*8
    const bf16_t* bp = Wb + (size_t)(cb * BN + (t >> 2)) * DD + (t & 3) * 8;
    // A DMA (ZB): row = row0 + q*64 + (t>>2)  (npad-padded, always in-bounds)
    const bf16_t* ap = zb + (size_t)(row0 + (t >> 2)) * DD + (t & 3) * 8;

    // A fallback (fp32): thread t -> row t>>1, k-half (t&1)*16 floats
    const int arow = t >> 1;
    const int ah   = t & 1;
    int rowe = row0 + arow; if (rowe >= N) rowe = N - 1;
    const float4* zp4 = (const float4*)(z + (size_t)rowe * DD + ah * 16);

    f32x4 acc[4][4];
    #pragma unroll
    for (int a = 0; a < 4; ++a)
        #pragma unroll
        for (int b = 0; b < 4; ++b) acc[a][b] = (f32x4){0.f, 0.f, 0.f, 0.f};

    float4 v0, v1, v2, v3;
    if (!ZB) { v0 = zp4[0]; v1 = zp4[1]; v2 = zp4[2]; v3 = zp4[3]; }

    for (int kc = 0; kc < DD; kc += BK) {
        if (kc) __syncthreads();        // #1: previous compute done, LDS reusable

        #pragma unroll
        for (int q = 0; q < 2; ++q) {   // B: 2 DMA rounds of 256 x 16 B
            int ldsoff = __builtin_amdgcn_readfirstlane(q * 4096 + wv * 1024);
            __builtin_amdgcn_global_load_lds(
                (const __attribute__((address_space(1))) unsigned int*)(const void*)(bp + (size_t)q * 64 * DD + kc),
                (__attribute__((address_space(3))) unsigned int*)(void*)((char*)Bs + ldsoff),
                16, 0, 0);
        }
        if (ZB) {
            #pragma unroll
            for (int q = 0; q < 2; ++q) {   // A: 2 DMA rounds of 256 x 16 B
                int ldsoff = __builtin_amdgcn_readfirstlane(q * 4096 + wv * 1024);
                __builtin_amdgcn_global_load_lds(
                    (const __attribute__((address_space(1))) unsigned int*)(const void*)(ap + (size_t)q * 64 * DD + kc),
                    (__attribute__((address_space(3))) unsigned int*)(void*)((char*)As + ldsoff),
                    16, 0, 0);
            }
        } else {
            bf16x8_t lo, hi;
            lo[0]=(bf16_t)v0.x; lo[1]=(bf16_t)v0.y; lo[2]=(bf16_t)v0.z; lo[3]=(bf16_t)v0.w;
            lo[4]=(bf16_t)v1.x; lo[5]=(bf16_t)v1.y; lo[6]=(bf16_t)v1.z; lo[7]=(bf16_t)v1.w;
            hi[0]=(bf16_t)v2.x; hi[1]=(bf16_t)v2.y; hi[2]=(bf16_t)v2.z; hi[3]=(bf16_t)v2.w;
            hi[4]=(bf16_t)v3.x; hi[5]=(bf16_t)v3.y; hi[6]=(bf16_t)v3.z; hi[7]=(bf16_t)v3.w;
            *(bf16x8_t*)(As + arow * BK + ah * 16)     = lo;
            *(bf16x8_t*)(As + arow * BK + ah * 16 + 8) = hi;
        }

        __syncthreads();                // #2: drains DMA (vmcnt) + LDS writes

        if (!ZB && kc + BK < DD) {
            int kf = (kc + BK) >> 2;
            v0 = zp4[kf]; v1 = zp4[kf + 1]; v2 = zp4[kf + 2]; v3 = zp4[kf + 3];
        }

        bf16x8_t af[4];
        #pragma unroll
        for (int rt = 0; rt < 4; ++rt)
            af[rt] = *(const bf16x8_t*)(As + (wr * 64 + rt * 16 + l15) * BK + quad * 8);
        #pragma unroll
        for (int ct = 0; ct < 4; ++ct) {
            bf16x8_t bfv = *(const bf16x8_t*)(Bs + (wc * 64 + ct * 16 + l15) * BK + quad * 8);
            #pragma unroll
            for (int rt = 0; rt < 4; ++rt)
                acc[rt][ct] = __builtin_amdgcn_mfma_f32_16x16x32_bf16(af[rt], bfv, acc[rt][ct], 0, 0, 0);
        }
    }

    // epilogue: x = acc + b[col]; per-row partial sq and dot(c) over this col-block
    float bc[4], cc[4];
    #pragma unroll
    for (int ct = 0; ct < 4; ++ct) {
        int col = cb * BN + wc * 64 + ct * 16 + l15;
        bc[ct] = bvec[col];
        cc[ct] = cvec[col];
    }
    #pragma unroll
    for (int rt = 0; rt < 4; ++rt) {
        #pragma unroll
        for (int rg = 0; rg < 4; ++rg) {
            float sq = 0.f, dt = 0.f;
            #pragma unroll
            for (int ct = 0; ct < 4; ++ct) {
                float x = acc[rt][ct][rg] + bc[ct];
                sq += x * x;
                dt += x * cc[ct];
            }
            #pragma unroll
            for (int off = 1; off < 16; off <<= 1) {
                sq += __shfl_xor(sq, off, 64);
                dt += __shfl_xor(dt, off, 64);
            }
            if (l15 == 0) {
                int rl = wr * 64 + rt * 16 + quad * 4 + rg;
                psq[rl][wc] = sq;
                pdt[rl][wc] = dt;
            }
        }
    }
    __syncthreads();
    if (t < BM) {
        int r = row0 + t;
        if (r < N) {
            sqp[(size_t)cb * npad + r] = psq[t][0] + psq[t][1];
            dtp[(size_t)cb * npad + r] = pdt[t][0] + pdt[t][1];
        }
    }
}

// ---------------- combine 4 col-block partials -> dist ----------------
__global__ void k_final(const float* __restrict__ sqp, const float* __restrict__ dtp,
                        const float* __restrict__ cninv, float* __restrict__ out,
                        int N, int npad) {
    int r = blockIdx.x * blockDim.x + threadIdx.x;
    if (r < N) {
        float sq = sqp[r] + sqp[(size_t)npad + r] + sqp[2 * (size_t)npad + r] + sqp[3 * (size_t)npad + r];
        float dt = dtp[r] + dtp[(size_t)npad + r] + dtp[2 * (size_t)npad + r] + dtp[3 * (size_t)npad + r];
        out[r] = 1.0f - dt * cninv[0] / fmaxf(sqrtf(sq), EPSF);
    }
}

extern "C" void kernel_launch(void* const* d_in, const int* in_sizes, int n_in,
                              void* d_out, int out_size, void* d_ws, size_t ws_size,
                              hipStream_t stream)
{
    const float* z = (const float*)d_in[0];
    const float* W = (const float*)d_in[1];
    const float* b = (const float*)d_in[2];
    float* out = (float*)d_out;
    int N = in_sizes[0] / DD;
    int npad = ((N + BM - 1) / BM) * BM;

    float* ws = (float*)d_ws;
    size_t off = 0;
    float* part  = ws + off; off += (size_t)NPART * DD;
    float* cbar  = ws + off; off += DD;
    float* d2    = ws + off; off += (size_t)npad;
    float* mpart = ws + off; off += NPART;
    float* spart = ws + off; off += NPART;
    float* d2min = ws + off; off += 1;
    float* sinvp = ws + off; off += 1;
    float* cvec  = ws + off; off += DD;
    float* cninv = ws + off; off += 1;
    off = (off + 3) & ~(size_t)3;
    float* sqp   = ws + off; off += (size_t)4 * npad;
    float* dtp   = ws + off; off += (size_t)4 * npad;
    bf16_t* Wb   = (bf16_t*)(ws + off); off += (size_t)DD * DD / 2;
    bf16_t* zb   = (bf16_t*)(ws + off);
    size_t need_bytes = (off + (size_t)npad * DD / 2) * sizeof(float);
    const bool use_zb = ws_size >= need_bytes;

    int rpb = (N + NPART - 1) / NPART;

    k_convW<<<256, 256, 0, stream>>>(W, Wb);
    if (use_zb) k_colsum<true ><<<NPART, 256, 0, stream>>>(z, zb, part, N, rpb);
    else        k_colsum<false><<<NPART, 256, 0, stream>>>(z, zb, part, N, rpb);
    k_reduceP<<<DD, 256, 0, stream>>>(part, cbar, 1.0f / (float)N);
    k_d2s<<<NPART, 256, 0, stream>>>(z, cbar, d2, mpart, spart, N);
    k_combine<<<1, 256, 0, stream>>>(mpart, spart, d2min, sinvp);
    if (use_zb) k_wcolsum_b<<<NPART, 256, 0, stream>>>(zb, d2, d2min, sinvp, part, N, rpb);
    else        k_wcolsum_f<<<NPART, 256, 0, stream>>>(z,  d2, d2min, sinvp, part, N, rpb);
    k_reduceP<<<DD, 256, 0, stream>>>(part, cvec, 1.0f);
    k_cnorm<<<1, DD, 0, stream>>>(cvec, cninv);
    dim3 grid(4, npad / BM);
    if (use_zb) k_gemm<true ><<<grid, 256, 0, stream>>>(z, zb, Wb, b, cvec, sqp, dtp, N, npad);
    else        k_gemm<false><<<grid, 256, 0, stream>>>(z, zb, Wb, b, cvec, sqp, dtp, N, npad);
    k_final<<<(N + 255) / 256, 256, 0, stream>>>(sqp, dtp, cninv, out, N, npad);
}